// Round 8
// baseline (1532.871 us; speedup 1.0000x reference)
//
#include <hip/hip_runtime.h>
#include <cstdint>

// ---------------- problem constants ----------------
#define NYD   256
#define NXD   256
#define PADC  22            // PML + FD_PAD
#define NYP_  300           // NY + 2*PAD
#define NXP_  300
#define NTT   250
#define NSHOT_ 2
#define NSRC_  8
#define NREC_  64
#define DT_   0.0005f

// guarded-array geometry
#define GDN   28
#define STP   356           // NXP_ + 2*GDN
#define FP    (STP*STP)     // per-shot field words

// fallback (r5) tile geometry: 64x4, 750 blocks
#define NTX   5
#define TPS   375
#define NWG   750

// persistent tile geometry: 64x16, 190 blocks of 512 threads
#define BY2   16
#define NTY2  19            // ceil(300/16)
#define TPS2  95            // 19*5 per shot
#define NWG2  190

// ---------------- agent-scope (cross-XCD coherent) access helpers ----------------
__device__ __forceinline__ unsigned long long ld_agent_u64(const float* p) {
    return __hip_atomic_load((const unsigned long long*)p,
                             __ATOMIC_RELAXED, __HIP_MEMORY_SCOPE_AGENT);
}
__device__ __forceinline__ void st_agent_f32(float* p, float v) {
    __hip_atomic_store((unsigned*)p, __float_as_uint(v),
                       __ATOMIC_RELAXED, __HIP_MEMORY_SCOPE_AGENT);
}

// ---------------- zero workspace ----------------
__global__ void zero_kernel(float* __restrict__ p, long n) {
    long i = (long)blockIdx.x * blockDim.x + threadIdx.x;
    long stride = (long)gridDim.x * blockDim.x;
    for (; i < n; i += stride) p[i] = 0.0f;
}

// ---------------- setup: v2dt2, PML profiles, src/rec tile bins (both geometries) ----------------
__global__ void populate_kernel(const float* __restrict__ v,
                                const int* __restrict__ srcloc,
                                const int* __restrict__ recloc,
                                float* __restrict__ v2dt2,
                                float* __restrict__ prof,
                                unsigned* __restrict__ srcb4,
                                unsigned long long* __restrict__ recb4,
                                unsigned* __restrict__ srcb16,
                                unsigned long long* __restrict__ recb16) {
    int i = blockIdx.x * 256 + threadIdx.x;

    if (i < NYP_ * NXP_) {
        int y = i / NXP_, x = i % NXP_;
        int vy = min(max(y - PADC, 0), NYD - 1);
        int vx = min(max(x - PADC, 0), NXD - 1);
        float vv = v[vy * NXD + vx];
        v2dt2[(y + GDN) * STP + (x + GDN)] = vv * vv * (DT_ * DT_);
    }

    if (i < NYP_) {
        float fi = (float)i;
        float d = fmaxf(22.0f - fi, fi - 277.0f);
        float frac = fminf(fmaxf(d * (1.0f / 20.0f), 0.0f), 1.0f);
        float sigma_max = 3.0f * 4000.0f * logf(1000.0f) / (2.0f * 20.0f * 5.0f);
        float sigma = sigma_max * frac * frac;
        float alpha = 3.14159265358979323846f * 25.0f * (1.0f - frac);
        float b = expf(-(sigma + alpha) * DT_);
        float a = sigma / (sigma + alpha + 1e-9f) * (b - 1.0f);
        prof[GDN + i] = a;
        prof[STP + GDN + i] = b;
    }

    if (i < NSHOT_ * NSRC_) {
        int sy = srcloc[2 * i] + PADC;
        int sx = srcloc[2 * i + 1] + PADC;
        int shot = i / NSRC_;
        atomicOr(&srcb4[shot * TPS + (sy / 4) * NTX + (sx / 64)], 1u << (i % NSRC_));
        atomicOr(&srcb16[shot * TPS2 + (sy / BY2) * 5 + (sx / 64)], 1u << (i % NSRC_));
    }

    if (i >= 1024 && i < 1024 + NSHOT_ * NREC_) {
        int j = i - 1024;
        int ry = recloc[2 * j] + PADC;
        int rx = recloc[2 * j + 1] + PADC;
        int shot = j / NREC_;
        atomicOr(&recb4[shot * TPS + (ry / 4) * NTX + (rx / 64)], 1ull << (j % NREC_));
        atomicOr(&recb16[shot * TPS2 + (ry / BY2) * 5 + (rx / 64)], 1ull << (j % NREC_));
    }
}

// ---------------- persistent kernel: LDS-resident tiles, halo-only exchange ----------------
// 190 blocks (16x64 tiles), 512 threads, 2 cells/thread. Tile interior (wf
// dbuf, psi in-place) lives in LDS for all 250 steps; only halos cross blocks
// via agent-scope UC accesses (stage 480x8B, publish ~900x4B per step).
// Per step: wait 4 neighbor flags >= it; stage halos; psi update (all rows
// incl halo rows, recomputed locally -> bitwise equal to neighbor's value,
// publish psi boundary); wf BOUNDARY cells first + publish; vmcnt(0)+barrier
// +flag (mid-step -> neighbors' polls overlap our interior work); wf interior.
// Anti-dependence: staging precedes flag-post within an iteration, so flag>=it
// guarantees the neighbor finished reading the parity buffer we overwrite
// (same argument as validated r7). Guard ring all-zero + prof/v2 zero there
// keeps Dirichlet exact; overhang cells publish exact zeros.
__global__ __launch_bounds__(512) void persist_kernel(
    float* wfA, float* wfB, float* pyA, float* pyB, float* pxA, float* pxB,
    const float* __restrict__ v2g, const float* __restrict__ profg,
    const unsigned* __restrict__ srcb, const unsigned long long* __restrict__ recb,
    int* prog,
    const int* __restrict__ srcloc, const int* __restrict__ recloc,
    const float* __restrict__ amps,   // [NSHOT][NSRC][NT]
    float* __restrict__ out) {        // [NSHOT][NREC][NT]
    const int me   = blockIdx.x;
    const int shot = me / TPS2;
    const int tl   = me - shot * TPS2;
    const int tyt  = tl / 5, txt = tl % 5;
    const int ty0  = tyt * BY2, tx0 = txt * 64;

    const int nUp = (tyt > 0)        ? me - 5 : me;
    const int nDn = (tyt < NTY2 - 1) ? me + 5 : me;
    const int nL  = (txt > 0)        ? me - 1 : me;
    const int nR  = (txt < 4)        ? me + 1 : me;

    __shared__ alignas(8) float swf[2][24][72]; // wf: rows ty0-4..+19, cols tx0-4..+67
    __shared__ alignas(8) float spy[20][64];    // psiy: rows ty0-2..+17, cols tx0..+63
    __shared__ alignas(8) float spx[16][68];    // psix: rows ty0..+15, cols tx0-2..+65
    __shared__ float sya[20], syb[20], sxa[68], sxb[68];
    __shared__ int   ssy[NSRC_], ssx[NSRC_], sry[NREC_], srx[NREC_];
    __shared__ unsigned sbs;
    __shared__ unsigned long long sbr;

    const int tid = threadIdx.x;
    const int lx = tid & 63, ly = tid >> 6;       // cells: rows ly and ly+8
    const bool edgecol = (lx < 4) || (lx >= 60);

    // ---- zero LDS state ----
    for (int k = tid; k < 2 * 24 * 72; k += 512) ((float*)swf)[k] = 0.0f;
    for (int k = tid; k < 20 * 64; k += 512) ((float*)spy)[k] = 0.0f;
    for (int k = tid; k < 16 * 68; k += 512) ((float*)spx)[k] = 0.0f;

    if (tid < 20) {
        sya[tid] = profg[GDN + ty0 - 2 + tid];
        syb[tid] = profg[STP + GDN + ty0 - 2 + tid];
    }
    if (tid < 68) {
        sxa[tid] = profg[GDN + tx0 - 2 + tid];
        sxb[tid] = profg[STP + GDN + tx0 - 2 + tid];
    }
    if (tid < NSRC_) {
        ssy[tid] = srcloc[(shot * NSRC_ + tid) * 2]     + PADC;
        ssx[tid] = srcloc[(shot * NSRC_ + tid) * 2 + 1] + PADC;
    }
    if (tid < NREC_) {
        sry[tid] = recloc[(shot * NREC_ + tid) * 2]     + PADC;
        srx[tid] = recloc[(shot * NREC_ + tid) * 2 + 1] + PADC;
    }
    if (tid == 0) { sbs = srcb[shot * TPS2 + tl]; sbr = recb[shot * TPS2 + tl]; }

    float zy0 = 0.f, zy1 = 0.f, zx0 = 0.f, zx1 = 0.f, wm0 = 0.f, wm1 = 0.f;
    const float vd0 = v2g[(ty0 + ly + GDN) * STP + (tx0 + lx + GDN)];
    const float vd1 = v2g[(ty0 + ly + 8 + GDN) * STP + (tx0 + lx + GDN)];

    float* wfr = wfA + shot * FP;  float* wfw = wfB + shot * FP;
    float* pyr = pyA + shot * FP;  float* pyw = pyB + shot * FP;
    float* pxr = pxA + shot * FP;  float* pxw = pxB + shot * FP;

    __syncthreads();

    const float ih  = 0.2f;    // 1/DY
    const float ih2 = 0.04f;   // 1/DY^2
    const float C1A = 2.0f / 3.0f, C1B = 1.0f / 12.0f;
    const float C2A = 4.0f / 3.0f, C2B = -1.0f / 12.0f, C2C = -2.5f;

    int cur = 0;

// one wf cell: compute wf(t+1)+zeta, store to LDS next-buf, optionally publish
#define DO_CELL(cc, PUB)                                                        \
    {                                                                           \
        const int yy = ly + 8 * cc;                                             \
        const int y = ty0 + yy, x = tx0 + lx;                                   \
        float wy[9], wx[9];                                                     \
        _Pragma("unroll")                                                       \
        for (int k = 0; k < 9; ++k) wy[k] = swf[cur][yy + k][lx + 4];           \
        _Pragma("unroll")                                                       \
        for (int k = 0; k < 9; ++k) wx[k] = (k == 4) ? wy[4] : swf[cur][yy + 4][lx + k]; \
        float d2y = (C2B * (wy[2] + wy[6]) + C2A * (wy[3] + wy[5]) + C2C * wy[4]) * ih2; \
        float d2x = (C2B * (wx[2] + wx[6]) + C2A * (wx[3] + wx[5]) + C2C * wx[4]) * ih2; \
        float dpsiy = (C1A * (spy[yy + 3][lx] - spy[yy + 1][lx])                \
                     - C1B * (spy[yy + 4][lx] - spy[yy][lx])) * ih;             \
        float dpsix = (C1A * (spx[yy][lx + 3] - spx[yy][lx + 1])                \
                     - C1B * (spx[yy][lx + 4] - spx[yy][lx])) * ih;             \
        float zyn = syb[yy + 2] * zy##cc + sya[yy + 2] * (d2y + dpsiy);         \
        float zxn = sxb[lx + 2] * zx##cc + sxa[lx + 2] * (d2x + dpsix);         \
        zy##cc = zyn; zx##cc = zxn;                                             \
        float lap = d2y + d2x + dpsiy + dpsix + zyn + zxn;                      \
        float wfp = 2.0f * wy[4] - wm##cc + vd##cc * lap;                       \
        if (sbs) {                                                              \
            _Pragma("unroll")                                                   \
            for (int q = 0; q < NSRC_; ++q)                                     \
                if ((sbs & (1u << q)) && ssy[q] == y && ssx[q] == x)            \
                    wfp += vd##cc * amps[(shot * NSRC_ + q) * NTT + it];        \
        }                                                                       \
        wm##cc = wy[4];                                                         \
        swf[cur ^ 1][yy + 4][lx + 4] = wfp;                                     \
        if (PUB) st_agent_f32(wfw + (y + GDN) * STP + (x + GDN), wfp);          \
        unsigned long long rb = sbr;                                            \
        while (rb) {                                                            \
            int r = __ffsll(rb) - 1; rb &= rb - 1;                              \
            if (sry[r] == y && srx[r] == x)                                     \
                out[(shot * NREC_ + r) * NTT + it] = wfp;                       \
        }                                                                       \
    }

#pragma unroll 1
    for (int it = 0; it < NTT; ++it) {
        // ---- 1: wait for neighbors' state it ----
        if (tid < 4) {
            const int nb = (tid == 0) ? nUp : (tid == 1) ? nDn : (tid == 2) ? nL : nR;
            while (__hip_atomic_load(&prog[nb], __ATOMIC_RELAXED, __HIP_MEMORY_SCOPE_AGENT) < it)
                __builtin_amdgcn_s_sleep(1);
        }
        __syncthreads();

        // ---- 2: stage halos only (480 x 8B agent loads) ----
        if (tid < 480) {
            if (tid < 256) {                       // wf top/bottom: 8 rows x 32 pairs
                int r8 = tid >> 5, p = tid & 31;
                int lr = (r8 < 4) ? r8 : 16 + r8;  // 0..3 / 20..23
                *(unsigned long long*)&swf[cur][lr][4 + 2 * p] =
                    ld_agent_u64(wfr + (ty0 - 4 + lr + GDN) * STP + (tx0 + GDN) + 2 * p);
            } else if (tid < 320) {                // wf left/right: 2 sides x 16 rows x 2 pairs
                int l = tid - 256; int side = l >> 5, rr = (l >> 1) & 15, p = l & 1;
                int lc = side ? 68 : 0; int gx = side ? tx0 + 64 : tx0 - 4;
                *(unsigned long long*)&swf[cur][4 + rr][lc + 2 * p] =
                    ld_agent_u64(wfr + (ty0 + rr + GDN) * STP + (gx + GDN) + 2 * p);
            } else if (tid < 448) {                // psiy top/bottom: 4 rows x 32 pairs
                int l = tid - 320; int r4 = l >> 5, p = l & 31;
                int lr = (r4 < 2) ? r4 : 16 + r4;  // 0,1 / 18,19
                *(unsigned long long*)&spy[lr][2 * p] =
                    ld_agent_u64(pyr + (ty0 - 2 + lr + GDN) * STP + (tx0 + GDN) + 2 * p);
            } else {                               // psix left/right: 2 sides x 16 rows
                int l = tid - 448; int side = l >> 4, rr = l & 15;
                int lc = side ? 66 : 0; int gx = side ? tx0 + 64 : tx0 - 2;
                *(unsigned long long*)&spx[rr][lc] =
                    ld_agent_u64(pxr + (ty0 + rr + GDN) * STP + (gx + GDN));
            }
        }
        __syncthreads();

        // ---- 3: psi(t)->psi(t+1) in place (all rows/cols incl halo), publish psi boundary ----
#pragma unroll
        for (int k = 0; k < 5; ++k) {
            int lin = tid + k * 512;
            if (lin < 1280) {                      // psiy: row r (y=ty0-2+r), col c (x=tx0+c)
                int r = lin >> 6, c = lin & 63;
                float dw = (C1A * (swf[cur][r + 3][c + 4] - swf[cur][r + 1][c + 4])
                          - C1B * (swf[cur][r + 4][c + 4] - swf[cur][r][c + 4])) * ih;
                float pv = syb[r] * spy[r][c] + sya[r] * dw;
                spy[r][c] = pv;
                if (r == 2 || r == 3 || r == 16 || r == 17)   // tile rows 0,1,14,15
                    st_agent_f32(pyw + (ty0 - 2 + r + GDN) * STP + (tx0 + c + GDN), pv);
            } else if (lin < 2368) {               // psix: row rr (y=ty0+rr), col c (x=tx0-2+c)
                int l = lin - 1280; int rr = l / 68, c = l % 68;
                float dw = (C1A * (swf[cur][rr + 4][c + 3] - swf[cur][rr + 4][c + 1])
                          - C1B * (swf[cur][rr + 4][c + 4] - swf[cur][rr + 4][c])) * ih;
                float pv = sxb[c] * spx[rr][c] + sxa[c] * dw;
                spx[rr][c] = pv;
                if (c == 2 || c == 3 || c == 64 || c == 65)   // tile cols 0,1,62,63
                    st_agent_f32(pxw + (ty0 + rr + GDN) * STP + (tx0 - 2 + c + GDN), pv);
            }
        }
        __syncthreads();

        // ---- 4: wf boundary cells first (rows 0-3,12-15 + edge cols), publish ----
        if (ly < 4) { DO_CELL(0, true) } else { DO_CELL(1, true) }
        if (edgecol) {
            if (ly < 4) { DO_CELL(1, true) } else { DO_CELL(0, true) }
        }

        // ---- 5: drain publishes, post flag (neighbors can proceed) ----
        asm volatile("s_waitcnt vmcnt(0)" ::: "memory");
        __syncthreads();
        if (tid == 0)
            __hip_atomic_store(&prog[me], it + 1, __ATOMIC_RELAXED, __HIP_MEMORY_SCOPE_AGENT);

        // ---- 6: wf interior cells (overlaps neighbors' flag polls) ----
        if (!edgecol) {
            if (ly < 4) { DO_CELL(1, false) } else { DO_CELL(0, false) }
        }
        __syncthreads();

        cur ^= 1;
        float* t0 = wfr; wfr = wfw; wfw = t0;
        float* t1 = pyr; pyr = pyw; pyw = t1;
        float* t2 = pxr; pxr = pxw; pxw = t2;
    }
#undef DO_CELL
}

// ---------------- fallback: verified r5 single-step kernel ----------------
__global__ __launch_bounds__(256) void step_kernel(
    const float* __restrict__ wfc_g, float* __restrict__ wfn_g,
    const float* __restrict__ pyr_g, float* __restrict__ pyw_g,
    const float* __restrict__ pxr_g, float* __restrict__ pxw_g,
    float* __restrict__ zy_g, float* __restrict__ zx_g,
    const float* __restrict__ v2_g, const float* __restrict__ prof,
    const unsigned* __restrict__ srcbin,
    const unsigned long long* __restrict__ recbin,
    const int* __restrict__ srcloc, const int* __restrict__ recloc,
    const float* __restrict__ amps, float* __restrict__ out, int t) {
    int orig = blockIdx.x;
    int xcd = orig & 7, idx = orig >> 3;
    int wgid = (xcd < 6) ? xcd * 94 + idx : 6 * 94 + (xcd - 6) * 93 + idx;
    int shot = wgid / TPS;
    int tl   = wgid - shot * TPS;
    int ty0  = (tl / NTX) * 4;
    int tx0  = (tl % NTX) * 64;

    const float* wfc = wfc_g + shot * FP;
    float*       wfn = wfn_g + shot * FP;
    const float* pyr = pyr_g + shot * FP;
    float*       pyw = pyw_g + shot * FP;
    const float* pxr = pxr_g + shot * FP;
    float*       pxw = pxw_g + shot * FP;
    float*       zyg = zy_g  + shot * FP;
    float*       zxg = zx_g  + shot * FP;

    __shared__ float swf[12][72];
    __shared__ float spy[8][64];
    __shared__ float spx[4][72];
    __shared__ float sya[8], syb[8], sxa[68], sxb[68];
    __shared__ int   ssy[NSRC_], ssx[NSRC_], sry[NREC_], srx[NREC_];
    __shared__ unsigned sbs;
    __shared__ unsigned long long sbr;

    const int tid = threadIdx.x;
    const int lx = tid & 63, ly = tid >> 6;
    const int y = ty0 + ly, x = tx0 + lx;
    const int g = (y + GDN) * STP + (x + GDN);

    float wm = wfn[g];
    float zy = zyg[g];
    float zx = zxg[g];
    float vd = v2_g[g];

    if (tid < 216) {
        int rr = tid / 18, cc = tid % 18;
        *reinterpret_cast<float4*>(&swf[rr][cc * 4]) =
            *(reinterpret_cast<const float4*>(wfc + (ty0 - 4 + rr + GDN) * STP + (tx0 - 4 + GDN)) + cc);
    }
    if (tid < 128) {
        int rr = tid / 16, cc = tid % 16;
        *reinterpret_cast<float4*>(&spy[rr][cc * 4]) =
            *(reinterpret_cast<const float4*>(pyr + (ty0 - 2 + rr + GDN) * STP + (tx0 + GDN)) + cc);
    }
    if (tid < 72) {
        int rr = tid / 18, cc = tid % 18;
        *reinterpret_cast<float4*>(&spx[rr][cc * 4]) =
            *(reinterpret_cast<const float4*>(pxr + (ty0 + rr + GDN) * STP + (tx0 - 4 + GDN)) + cc);
    }
    if (tid < 8) {
        sya[tid] = prof[GDN + ty0 - 2 + tid];
        syb[tid] = prof[STP + GDN + ty0 - 2 + tid];
        ssy[tid] = srcloc[(shot * NSRC_ + tid) * 2]     + PADC;
        ssx[tid] = srcloc[(shot * NSRC_ + tid) * 2 + 1] + PADC;
    }
    if (tid < 68) {
        sxa[tid] = prof[GDN + tx0 - 2 + tid];
        sxb[tid] = prof[STP + GDN + tx0 - 2 + tid];
    }
    if (tid < NREC_) {
        sry[tid] = recloc[(shot * NREC_ + tid) * 2]     + PADC;
        srx[tid] = recloc[(shot * NREC_ + tid) * 2 + 1] + PADC;
    }
    if (tid == 0) { sbs = srcbin[shot * TPS + tl]; sbr = recbin[shot * TPS + tl]; }
    __syncthreads();

    const float ih = 0.2f, ih2 = 0.04f;
    const float C1A = 2.0f / 3.0f, C1B = 1.0f / 12.0f;
    const float C2A = 4.0f / 3.0f, C2B = -1.0f / 12.0f, C2C = -2.5f;

    float wy[9];
#pragma unroll
    for (int k = 0; k < 9; k++) wy[k] = swf[ly + k][lx + 4];
    float wx[9];
#pragma unroll
    for (int k = 0; k < 9; k++) wx[k] = (k == 4) ? wy[4] : swf[ly + 4][lx + k];

    float d2y = (C2B * (wy[2] + wy[6]) + C2A * (wy[3] + wy[5]) + C2C * wy[4]) * ih2;
    float d2x = (C2B * (wx[2] + wx[6]) + C2A * (wx[3] + wx[5]) + C2C * wx[4]) * ih2;

    float pny[5], pnx[5];
#pragma unroll
    for (int j = 0; j < 5; j++) {
        float dwdy = (C1A * (wy[j + 3] - wy[j + 1]) - C1B * (wy[j + 4] - wy[j])) * ih;
        pny[j] = syb[ly + j] * spy[ly + j][lx] + sya[ly + j] * dwdy;
        float dwdx = (C1A * (wx[j + 3] - wx[j + 1]) - C1B * (wx[j + 4] - wx[j])) * ih;
        pnx[j] = sxb[lx + j] * spx[ly][lx + j + 2] + sxa[lx + j] * dwdx;
    }

    float dpsiy = (C1A * (pny[3] - pny[1]) - C1B * (pny[4] - pny[0])) * ih;
    float dpsix = (C1A * (pnx[3] - pnx[1]) - C1B * (pnx[4] - pnx[0])) * ih;

    float ay_ = sya[ly + 2], by_ = syb[ly + 2];
    float ax_ = sxa[lx + 2], bx_ = sxb[lx + 2];

    zy = by_ * zy + ay_ * (d2y + dpsiy);
    zx = bx_ * zx + ax_ * (d2x + dpsix);

    float lap = d2y + d2x + dpsiy + dpsix + zy + zx;
    float wfp = 2.0f * wy[4] - wm + vd * lap;

    if (sbs) {
#pragma unroll
        for (int q = 0; q < NSRC_; q++)
            if ((sbs & (1u << q)) && ssy[q] == y && ssx[q] == x)
                wfp += vd * amps[(shot * NSRC_ + q) * NTT + t];
    }

    wfn[g] = wfp;
    pyw[g] = pny[2];
    pxw[g] = pnx[2];
    zyg[g] = zy;
    zxg[g] = zx;

    unsigned long long rb = sbr;
    while (rb) {
        int r = __ffsll(rb) - 1;
        rb &= rb - 1;
        if (sry[r] == y && srx[r] == x)
            out[(shot * NREC_ + r) * NTT + t] = wfp;
    }
}

// ---------------- host ----------------
extern "C" void kernel_launch(void* const* d_in, const int* in_sizes, int n_in,
                              void* d_out, int out_size, void* d_ws, size_t ws_size,
                              hipStream_t stream) {
    const float* v      = (const float*)d_in[0];
    const float* amps   = (const float*)d_in[1];
    const int*   srcloc = (const int*)d_in[2];
    const int*   recloc = (const int*)d_in[3];
    float* out = (float*)d_out;

    float* base = (float*)d_ws;
    float* WF0 = base;
    float* WF1 = WF0 + 2L * FP;
    float* PY0 = WF1 + 2L * FP;
    float* PY1 = PY0 + 2L * FP;
    float* PX0 = PY1 + 2L * FP;
    float* PX1 = PX0 + 2L * FP;
    float* ZY  = PX1 + 2L * FP;    // fallback only
    float* ZX  = ZY  + 2L * FP;    // fallback only
    float* V2  = ZX  + 2L * FP;
    float* PROF = V2 + FP;         // [2*STP]
    unsigned long long* RECB4  = (unsigned long long*)(PROF + 2 * STP);   // 750 ull
    unsigned long long* RECB16 = RECB4 + NSHOT_ * TPS;                    // 190 ull
    unsigned* SRCB4  = (unsigned*)(RECB16 + NSHOT_ * TPS2);               // 750 u32
    unsigned* SRCB16 = SRCB4 + NSHOT_ * TPS;                              // 190 u32
    int*      PROG   = (int*)(SRCB16 + NSHOT_ * TPS2);                    // 190 int

    const long total_words = 17L * FP + 2 * STP
                           + 2L * NSHOT_ * TPS + 2L * NSHOT_ * TPS2
                           + NSHOT_ * TPS + NSHOT_ * TPS2
                           + NWG2;

    zero_kernel<<<2048, 256, 0, stream>>>(base, total_words);
    populate_kernel<<<(NYP_ * NXP_ + 255) / 256, 256, 0, stream>>>(
        v, srcloc, recloc, V2, PROF, SRCB4, RECB4, SRCB16, RECB16);

    // ---- preferred: one persistent cooperative kernel, halo-only exchange ----
    void* args[] = {
        (void*)&WF0, (void*)&WF1, (void*)&PY0, (void*)&PY1, (void*)&PX0, (void*)&PX1,
        (void*)&V2, (void*)&PROF, (void*)&SRCB16, (void*)&RECB16, (void*)&PROG,
        (void*)&srcloc, (void*)&recloc, (void*)&amps, (void*)&out
    };
    hipError_t e = hipLaunchCooperativeKernel((void*)persist_kernel,
                                              dim3(NWG2), dim3(512), args, 0, stream);

    // ---- fallback: verified r5 250-launch loop ----
    if (e != hipSuccess) {
        for (int t = 0; t < NTT; t++) {
            const bool o = (t & 1);
            step_kernel<<<NWG, 256, 0, stream>>>(
                o ? WF1 : WF0, o ? WF0 : WF1,
                o ? PY1 : PY0, o ? PY0 : PY1,
                o ? PX1 : PX0, o ? PX0 : PX1,
                ZY, ZX, V2, PROF, SRCB4, RECB4,
                srcloc, recloc, amps, out, t);
        }
    }
}

// Round 10
// 1498.765 us; speedup vs baseline: 1.0228x; 1.0228x over previous
//
#include <hip/hip_runtime.h>
#include <cstdint>

// ---------------- problem constants ----------------
#define NYD   256
#define NXD   256
#define PADC  22            // PML + FD_PAD
#define NYP_  300           // NY + 2*PAD
#define NXP_  300
#define NTT   250
#define NSHOT_ 2
#define NSRC_  8
#define NREC_  64
#define DT_   0.0005f

// guarded-array geometry
#define GDN   28
#define STP   356           // NXP_ + 2*GDN
#define FP    (STP*STP)     // per-shot field words

// fallback (r5) tile geometry: 64x4, 750 blocks
#define NTX   5
#define TPS   375
#define NWG   750

// persistent tile geometry: 64x16, 190 blocks of 512 threads
#define BY2   16
#define NTY2  19            // ceil(300/16)
#define TPS2  95            // 19*5 per shot
#define NWG2  190

// ---------------- agent-scope (cross-XCD coherent) access helpers ----------------
__device__ __forceinline__ unsigned long long ld_agent_u64(const float* p) {
    return __hip_atomic_load((const unsigned long long*)p,
                             __ATOMIC_RELAXED, __HIP_MEMORY_SCOPE_AGENT);
}
__device__ __forceinline__ void st_agent_f32(float* p, float v) {
    __hip_atomic_store((unsigned*)p, __float_as_uint(v),
                       __ATOMIC_RELAXED, __HIP_MEMORY_SCOPE_AGENT);
}

// ---------------- zero workspace ----------------
__global__ void zero_kernel(float* __restrict__ p, long n) {
    long i = (long)blockIdx.x * blockDim.x + threadIdx.x;
    long stride = (long)gridDim.x * blockDim.x;
    for (; i < n; i += stride) p[i] = 0.0f;
}

// ---------------- setup: v2dt2, PML profiles, src/rec tile bins (both geometries) ----------------
__global__ void populate_kernel(const float* __restrict__ v,
                                const int* __restrict__ srcloc,
                                const int* __restrict__ recloc,
                                float* __restrict__ v2dt2,
                                float* __restrict__ prof,
                                unsigned* __restrict__ srcb4,
                                unsigned long long* __restrict__ recb4,
                                unsigned* __restrict__ srcb16,
                                unsigned long long* __restrict__ recb16) {
    int i = blockIdx.x * 256 + threadIdx.x;

    if (i < NYP_ * NXP_) {
        int y = i / NXP_, x = i % NXP_;
        int vy = min(max(y - PADC, 0), NYD - 1);
        int vx = min(max(x - PADC, 0), NXD - 1);
        float vv = v[vy * NXD + vx];
        v2dt2[(y + GDN) * STP + (x + GDN)] = vv * vv * (DT_ * DT_);
    }

    if (i < NYP_) {
        float fi = (float)i;
        float d = fmaxf(22.0f - fi, fi - 277.0f);
        float frac = fminf(fmaxf(d * (1.0f / 20.0f), 0.0f), 1.0f);
        float sigma_max = 3.0f * 4000.0f * logf(1000.0f) / (2.0f * 20.0f * 5.0f);
        float sigma = sigma_max * frac * frac;
        float alpha = 3.14159265358979323846f * 25.0f * (1.0f - frac);
        float b = expf(-(sigma + alpha) * DT_);
        float a = sigma / (sigma + alpha + 1e-9f) * (b - 1.0f);
        prof[GDN + i] = a;
        prof[STP + GDN + i] = b;
    }

    if (i < NSHOT_ * NSRC_) {
        int sy = srcloc[2 * i] + PADC;
        int sx = srcloc[2 * i + 1] + PADC;
        int shot = i / NSRC_;
        atomicOr(&srcb4[shot * TPS + (sy / 4) * NTX + (sx / 64)], 1u << (i % NSRC_));
        atomicOr(&srcb16[shot * TPS2 + (sy / BY2) * 5 + (sx / 64)], 1u << (i % NSRC_));
    }

    if (i >= 1024 && i < 1024 + NSHOT_ * NREC_) {
        int j = i - 1024;
        int ry = recloc[2 * j] + PADC;
        int rx = recloc[2 * j + 1] + PADC;
        int shot = j / NREC_;
        atomicOr(&recb4[shot * TPS + (ry / 4) * NTX + (rx / 64)], 1ull << (j % NREC_));
        atomicOr(&recb16[shot * TPS2 + (ry / BY2) * 5 + (rx / 64)], 1ull << (j % NREC_));
    }
}

// ---------------- persistent kernel: single compute phase (merged psi) ----------------
// Protocol byte-identical to validated r8 (flags with s_sleep poll, global
// ping-pong, staged halo sets, published boundary sets, boundary-first +
// mid-step flag post). Change vs r8: the separate psi phase is merged into
// the cell compute using r5's verified pny/pnx halo-recompute; psi is LDS
// double-buffered. Removes one phase + barrier + the serialized psi publish
// pass (r8's 4.3M bank conflicts). Trailing barrier retained for safety.
__global__ __launch_bounds__(512) void persist_kernel(
    float* wfA, float* wfB, float* pyA, float* pyB, float* pxA, float* pxB,
    const float* __restrict__ v2g, const float* __restrict__ profg,
    const unsigned* __restrict__ srcb, const unsigned long long* __restrict__ recb,
    int* prog,
    const int* __restrict__ srcloc, const int* __restrict__ recloc,
    const float* __restrict__ amps,   // [NSHOT][NSRC][NT]
    float* __restrict__ out) {        // [NSHOT][NREC][NT]
    const int me   = blockIdx.x;
    const int shot = me / TPS2;
    const int tl   = me - shot * TPS2;
    const int tyt  = tl / 5, txt = tl % 5;
    const int ty0  = tyt * BY2, tx0 = txt * 64;

    const int nUp = (tyt > 0)        ? me - 5 : me;
    const int nDn = (tyt < NTY2 - 1) ? me + 5 : me;
    const int nL  = (txt > 0)        ? me - 1 : me;
    const int nR  = (txt < 4)        ? me + 1 : me;

    __shared__ alignas(8) float swf[2][24][74]; // wf rows ty0-4..+19, cols tx0-4..+67 (pad 74)
    __shared__ alignas(8) float spy[2][20][64]; // psiy rows ty0-2..+17, cols tx0..+63
    __shared__ alignas(8) float spx[2][16][70]; // psix rows ty0..+15, cols tx0-2..+65 (pad 70)
    __shared__ float sya[20], syb[20], sxa[68], sxb[68];
    __shared__ int   ssy[NSRC_], ssx[NSRC_], sry[NREC_], srx[NREC_];
    __shared__ unsigned sbs;
    __shared__ unsigned long long sbr;

    const int tid = threadIdx.x;
    const int lx = tid & 63, ly = tid >> 6;       // cells: rows ly and ly+8
    const bool edgecol = (lx < 4) || (lx >= 60);

    // ---- zero LDS state ----
    for (int k = tid; k < 2 * 24 * 74; k += 512) ((float*)swf)[k] = 0.0f;
    for (int k = tid; k < 2 * 20 * 64; k += 512) ((float*)spy)[k] = 0.0f;
    for (int k = tid; k < 2 * 16 * 70; k += 512) ((float*)spx)[k] = 0.0f;

    if (tid < 20) {
        sya[tid] = profg[GDN + ty0 - 2 + tid];
        syb[tid] = profg[STP + GDN + ty0 - 2 + tid];
    }
    if (tid < 68) {
        sxa[tid] = profg[GDN + tx0 - 2 + tid];
        sxb[tid] = profg[STP + GDN + tx0 - 2 + tid];
    }
    if (tid < NSRC_) {
        ssy[tid] = srcloc[(shot * NSRC_ + tid) * 2]     + PADC;
        ssx[tid] = srcloc[(shot * NSRC_ + tid) * 2 + 1] + PADC;
    }
    if (tid < NREC_) {
        sry[tid] = recloc[(shot * NREC_ + tid) * 2]     + PADC;
        srx[tid] = recloc[(shot * NREC_ + tid) * 2 + 1] + PADC;
    }
    if (tid == 0) { sbs = srcb[shot * TPS2 + tl]; sbr = recb[shot * TPS2 + tl]; }

    float zy0 = 0.f, zy1 = 0.f, zx0 = 0.f, zx1 = 0.f, wm0 = 0.f, wm1 = 0.f;
    const float vd0 = v2g[(ty0 + ly + GDN) * STP + (tx0 + lx + GDN)];
    const float vd1 = v2g[(ty0 + ly + 8 + GDN) * STP + (tx0 + lx + GDN)];

    float* wfr = wfA + shot * FP;  float* wfw = wfB + shot * FP;
    float* pyrg = pyA + shot * FP; float* pywg = pyB + shot * FP;
    float* pxrg = pxA + shot * FP; float* pxwg = pxB + shot * FP;

    __syncthreads();

    const float ih  = 0.2f;    // 1/DY
    const float ih2 = 0.04f;   // 1/DY^2
    const float C1A = 2.0f / 3.0f, C1B = 1.0f / 12.0f;
    const float C2A = 4.0f / 3.0f, C2B = -1.0f / 12.0f, C2C = -2.5f;

    int cs = 0;

// one cell: full r5 step body (verified math). Reads swf[cs], spy[pr], spx[pr];
// writes swf[cs^1]/spy[pw]/spx[pw] at own cell; publishes boundary sets if PUB.
#define DO_CELL(cc, PUB)                                                        \
    {                                                                           \
        const int yy = ly + 8 * cc;                                             \
        const int y = ty0 + yy, x = tx0 + lx;                                   \
        float wy[9], wx[9];                                                     \
        _Pragma("unroll")                                                       \
        for (int k = 0; k < 9; ++k) wy[k] = swf[cs][yy + k][lx + 4];            \
        _Pragma("unroll")                                                       \
        for (int k = 0; k < 9; ++k) wx[k] = (k == 4) ? wy[4] : swf[cs][yy + 4][lx + k]; \
        float d2y = (C2B * (wy[2] + wy[6]) + C2A * (wy[3] + wy[5]) + C2C * wy[4]) * ih2; \
        float d2x = (C2B * (wx[2] + wx[6]) + C2A * (wx[3] + wx[5]) + C2C * wx[4]) * ih2; \
        float pny[5], pnx[5];                                                   \
        _Pragma("unroll")                                                       \
        for (int j = 0; j < 5; ++j) {                                           \
            float dwdy = (C1A * (wy[j + 3] - wy[j + 1]) - C1B * (wy[j + 4] - wy[j])) * ih; \
            pny[j] = syb[yy + j] * spy[pr][yy + j][lx] + sya[yy + j] * dwdy;    \
            float dwdx = (C1A * (wx[j + 3] - wx[j + 1]) - C1B * (wx[j + 4] - wx[j])) * ih; \
            pnx[j] = sxb[lx + j] * spx[pr][yy][lx + j] + sxa[lx + j] * dwdx;    \
        }                                                                       \
        float dpsiy = (C1A * (pny[3] - pny[1]) - C1B * (pny[4] - pny[0])) * ih; \
        float dpsix = (C1A * (pnx[3] - pnx[1]) - C1B * (pnx[4] - pnx[0])) * ih; \
        float zyn = syb[yy + 2] * zy##cc + sya[yy + 2] * (d2y + dpsiy);         \
        float zxn = sxb[lx + 2] * zx##cc + sxa[lx + 2] * (d2x + dpsix);         \
        zy##cc = zyn; zx##cc = zxn;                                             \
        float lap = d2y + d2x + dpsiy + dpsix + zyn + zxn;                      \
        float wfp = 2.0f * wy[4] - wm##cc + vd##cc * lap;                       \
        if (sbs) {                                                              \
            _Pragma("unroll")                                                   \
            for (int q = 0; q < NSRC_; ++q)                                     \
                if ((sbs & (1u << q)) && ssy[q] == y && ssx[q] == x)            \
                    wfp += vd##cc * amps[(shot * NSRC_ + q) * NTT + it];        \
        }                                                                       \
        wm##cc = wy[4];                                                         \
        swf[cs ^ 1][yy + 4][lx + 4] = wfp;                                      \
        spy[pw][yy + 2][lx] = pny[2];                                           \
        spx[pw][yy][lx + 2] = pnx[2];                                           \
        if (PUB) {                                                              \
            const int g = (y + GDN) * STP + (x + GDN);                          \
            st_agent_f32(wfw + g, wfp);                                         \
            if (yy == 0 || yy == 1 || yy == 14 || yy == 15)                     \
                st_agent_f32(pywg + g, pny[2]);                                 \
            if (lx < 2 || lx >= 62)                                             \
                st_agent_f32(pxwg + g, pnx[2]);                                 \
        }                                                                       \
        unsigned long long rb = sbr;                                            \
        while (rb) {                                                            \
            int r = __ffsll(rb) - 1; rb &= rb - 1;                              \
            if (sry[r] == y && srx[r] == x)                                     \
                out[(shot * NREC_ + r) * NTT + it] = wfp;                       \
        }                                                                       \
    }

#pragma unroll 1
    for (int it = 0; it < NTT; ++it) {
        const int pr = it & 1, pw = pr ^ 1;

        // ---- 1: wait for neighbors' state it (s_sleep poll, r8-validated) ----
        if (tid < 4) {
            const int nb = (tid == 0) ? nUp : (tid == 1) ? nDn : (tid == 2) ? nL : nR;
            while (__hip_atomic_load(&prog[nb], __ATOMIC_RELAXED, __HIP_MEMORY_SCOPE_AGENT) < it)
                __builtin_amdgcn_s_sleep(1);
        }
        __syncthreads();

        // ---- 2: stage halos only (480 x 8B agent loads; r8-validated sets) ----
        if (tid < 480) {
            if (tid < 256) {                       // wf top/bottom: 8 rows x 32 pairs
                int r8 = tid >> 5, p = tid & 31;
                int lr = (r8 < 4) ? r8 : 16 + r8;  // 0..3 / 20..23
                *(unsigned long long*)&swf[cs][lr][4 + 2 * p] =
                    ld_agent_u64(wfr + (ty0 - 4 + lr + GDN) * STP + (tx0 + GDN) + 2 * p);
            } else if (tid < 320) {                // wf left/right: 2 sides x 16 rows x 2 pairs
                int l = tid - 256; int side = l >> 5, rr = (l >> 1) & 15, p = l & 1;
                int lc = side ? 68 : 0; int gx = side ? tx0 + 64 : tx0 - 4;
                *(unsigned long long*)&swf[cs][4 + rr][lc + 2 * p] =
                    ld_agent_u64(wfr + (ty0 + rr + GDN) * STP + (gx + GDN) + 2 * p);
            } else if (tid < 448) {                // psiy top/bottom: 4 rows x 32 pairs
                int l = tid - 320; int r4 = l >> 5, p = l & 31;
                int lr = (r4 < 2) ? r4 : 16 + r4;  // 0,1 / 18,19
                *(unsigned long long*)&spy[pr][lr][2 * p] =
                    ld_agent_u64(pyrg + (ty0 - 2 + lr + GDN) * STP + (tx0 + GDN) + 2 * p);
            } else {                               // psix left/right: 2 sides x 16 rows
                int l = tid - 448; int side = l >> 4, rr = l & 15;
                int lc = side ? 66 : 0; int gx = side ? tx0 + 64 : tx0 - 2;
                *(unsigned long long*)&spx[pr][rr][lc] =
                    ld_agent_u64(pxrg + (ty0 + rr + GDN) * STP + (gx + GDN));
            }
        }
        __syncthreads();

        // ---- 3: boundary cells (rows 0-3,12-15 + edge cols), publish ----
        if (ly < 4) { DO_CELL(0, true) } else { DO_CELL(1, true) }
        if (edgecol) {
            if (ly < 4) { DO_CELL(1, true) } else { DO_CELL(0, true) }
        }

        // ---- 4: drain publishes, post flag ----
        asm volatile("s_waitcnt vmcnt(0)" ::: "memory");
        __syncthreads();
        if (tid == 0)
            __hip_atomic_store(&prog[me], it + 1, __ATOMIC_RELAXED, __HIP_MEMORY_SCOPE_AGENT);

        // ---- 5: interior cells (overlaps neighbors' polls; no publish) ----
        if (!edgecol) {
            if (ly < 4) { DO_CELL(1, false) } else { DO_CELL(0, false) }
        }
        __syncthreads();   // safety: order phase-5 LDS writes vs next-step staging

        cs ^= 1;
        float* t0 = wfr; wfr = wfw; wfw = t0;
        float* t1 = pyrg; pyrg = pywg; pywg = t1;
        float* t2 = pxrg; pxrg = pxwg; pxwg = t2;
    }
#undef DO_CELL
}

// ---------------- fallback: verified r5 single-step kernel ----------------
__global__ __launch_bounds__(256) void step_kernel(
    const float* __restrict__ wfc_g, float* __restrict__ wfn_g,
    const float* __restrict__ pyr_g, float* __restrict__ pyw_g,
    const float* __restrict__ pxr_g, float* __restrict__ pxw_g,
    float* __restrict__ zy_g, float* __restrict__ zx_g,
    const float* __restrict__ v2_g, const float* __restrict__ prof,
    const unsigned* __restrict__ srcbin,
    const unsigned long long* __restrict__ recbin,
    const int* __restrict__ srcloc, const int* __restrict__ recloc,
    const float* __restrict__ amps, float* __restrict__ out, int t) {
    int orig = blockIdx.x;
    int xcd = orig & 7, idx = orig >> 3;
    int wgid = (xcd < 6) ? xcd * 94 + idx : 6 * 94 + (xcd - 6) * 93 + idx;
    int shot = wgid / TPS;
    int tl   = wgid - shot * TPS;
    int ty0  = (tl / NTX) * 4;
    int tx0  = (tl % NTX) * 64;

    const float* wfc = wfc_g + shot * FP;
    float*       wfn = wfn_g + shot * FP;
    const float* pyr = pyr_g + shot * FP;
    float*       pyw = pyw_g + shot * FP;
    const float* pxr = pxr_g + shot * FP;
    float*       pxw = pxw_g + shot * FP;
    float*       zyg = zy_g  + shot * FP;
    float*       zxg = zx_g  + shot * FP;

    __shared__ float swf[12][72];
    __shared__ float spy[8][64];
    __shared__ float spx[4][72];
    __shared__ float sya[8], syb[8], sxa[68], sxb[68];
    __shared__ int   ssy[NSRC_], ssx[NSRC_], sry[NREC_], srx[NREC_];
    __shared__ unsigned sbs;
    __shared__ unsigned long long sbr;

    const int tid = threadIdx.x;
    const int lx = tid & 63, ly = tid >> 6;
    const int y = ty0 + ly, x = tx0 + lx;
    const int g = (y + GDN) * STP + (x + GDN);

    float wm = wfn[g];
    float zy = zyg[g];
    float zx = zxg[g];
    float vd = v2_g[g];

    if (tid < 216) {
        int rr = tid / 18, cc = tid % 18;
        *reinterpret_cast<float4*>(&swf[rr][cc * 4]) =
            *(reinterpret_cast<const float4*>(wfc + (ty0 - 4 + rr + GDN) * STP + (tx0 - 4 + GDN)) + cc);
    }
    if (tid < 128) {
        int rr = tid / 16, cc = tid % 16;
        *reinterpret_cast<float4*>(&spy[rr][cc * 4]) =
            *(reinterpret_cast<const float4*>(pyr + (ty0 - 2 + rr + GDN) * STP + (tx0 + GDN)) + cc);
    }
    if (tid < 72) {
        int rr = tid / 18, cc = tid % 18;
        *reinterpret_cast<float4*>(&spx[rr][cc * 4]) =
            *(reinterpret_cast<const float4*>(pxr + (ty0 + rr + GDN) * STP + (tx0 - 4 + GDN)) + cc);
    }
    if (tid < 8) {
        sya[tid] = prof[GDN + ty0 - 2 + tid];
        syb[tid] = prof[STP + GDN + ty0 - 2 + tid];
        ssy[tid] = srcloc[(shot * NSRC_ + tid) * 2]     + PADC;
        ssx[tid] = srcloc[(shot * NSRC_ + tid) * 2 + 1] + PADC;
    }
    if (tid < 68) {
        sxa[tid] = prof[GDN + tx0 - 2 + tid];
        sxb[tid] = prof[STP + GDN + tx0 - 2 + tid];
    }
    if (tid < NREC_) {
        sry[tid] = recloc[(shot * NREC_ + tid) * 2]     + PADC;
        srx[tid] = recloc[(shot * NREC_ + tid) * 2 + 1] + PADC;
    }
    if (tid == 0) { sbs = srcbin[shot * TPS + tl]; sbr = recbin[shot * TPS + tl]; }
    __syncthreads();

    const float ih = 0.2f, ih2 = 0.04f;
    const float C1A = 2.0f / 3.0f, C1B = 1.0f / 12.0f;
    const float C2A = 4.0f / 3.0f, C2B = -1.0f / 12.0f, C2C = -2.5f;

    float wy[9];
#pragma unroll
    for (int k = 0; k < 9; k++) wy[k] = swf[ly + k][lx + 4];
    float wx[9];
#pragma unroll
    for (int k = 0; k < 9; k++) wx[k] = (k == 4) ? wy[4] : swf[ly + 4][lx + k];

    float d2y = (C2B * (wy[2] + wy[6]) + C2A * (wy[3] + wy[5]) + C2C * wy[4]) * ih2;
    float d2x = (C2B * (wx[2] + wx[6]) + C2A * (wx[3] + wx[5]) + C2C * wx[4]) * ih2;

    float pny[5], pnx[5];
#pragma unroll
    for (int j = 0; j < 5; j++) {
        float dwdy = (C1A * (wy[j + 3] - wy[j + 1]) - C1B * (wy[j + 4] - wy[j])) * ih;
        pny[j] = syb[ly + j] * spy[ly + j][lx] + sya[ly + j] * dwdy;
        float dwdx = (C1A * (wx[j + 3] - wx[j + 1]) - C1B * (wx[j + 4] - wx[j])) * ih;
        pnx[j] = sxb[lx + j] * spx[ly][lx + j + 2] + sxa[lx + j] * dwdx;
    }

    float dpsiy = (C1A * (pny[3] - pny[1]) - C1B * (pny[4] - pny[0])) * ih;
    float dpsix = (C1A * (pnx[3] - pnx[1]) - C1B * (pnx[4] - pnx[0])) * ih;

    float ay_ = sya[ly + 2], by_ = syb[ly + 2];
    float ax_ = sxa[lx + 2], bx_ = sxb[lx + 2];

    zy = by_ * zy + ay_ * (d2y + dpsiy);
    zx = bx_ * zx + ax_ * (d2x + dpsix);

    float lap = d2y + d2x + dpsiy + dpsix + zy + zx;
    float wfp = 2.0f * wy[4] - wm + vd * lap;

    if (sbs) {
#pragma unroll
        for (int q = 0; q < NSRC_; q++)
            if ((sbs & (1u << q)) && ssy[q] == y && ssx[q] == x)
                wfp += vd * amps[(shot * NSRC_ + q) * NTT + t];
    }

    wfn[g] = wfp;
    pyw[g] = pny[2];
    pxw[g] = pnx[2];
    zyg[g] = zy;
    zxg[g] = zx;

    unsigned long long rb = sbr;
    while (rb) {
        int r = __ffsll(rb) - 1;
        rb &= rb - 1;
        if (sry[r] == y && srx[r] == x)
            out[(shot * NREC_ + r) * NTT + t] = wfp;
    }
}

// ---------------- host ----------------
extern "C" void kernel_launch(void* const* d_in, const int* in_sizes, int n_in,
                              void* d_out, int out_size, void* d_ws, size_t ws_size,
                              hipStream_t stream) {
    const float* v      = (const float*)d_in[0];
    const float* amps   = (const float*)d_in[1];
    const int*   srcloc = (const int*)d_in[2];
    const int*   recloc = (const int*)d_in[3];
    float* out = (float*)d_out;

    float* base = (float*)d_ws;
    float* WF0 = base;
    float* WF1 = WF0 + 2L * FP;
    float* PY0 = WF1 + 2L * FP;
    float* PY1 = PY0 + 2L * FP;
    float* PX0 = PY1 + 2L * FP;
    float* PX1 = PX0 + 2L * FP;
    float* ZY  = PX1 + 2L * FP;    // fallback only
    float* ZX  = ZY  + 2L * FP;    // fallback only
    float* V2  = ZX  + 2L * FP;
    float* PROF = V2 + FP;         // [2*STP]
    unsigned long long* RECB4  = (unsigned long long*)(PROF + 2 * STP);   // 750 ull
    unsigned long long* RECB16 = RECB4 + NSHOT_ * TPS;                    // 190 ull
    unsigned* SRCB4  = (unsigned*)(RECB16 + NSHOT_ * TPS2);               // 750 u32
    unsigned* SRCB16 = SRCB4 + NSHOT_ * TPS;                              // 190 u32
    int*      PROG   = (int*)(SRCB16 + NSHOT_ * TPS2);                    // 190 int

    const long total_words = 17L * FP + 2 * STP
                           + 2L * NSHOT_ * TPS + 2L * NSHOT_ * TPS2
                           + NSHOT_ * TPS + NSHOT_ * TPS2
                           + NWG2;

    zero_kernel<<<2048, 256, 0, stream>>>(base, total_words);
    populate_kernel<<<(NYP_ * NXP_ + 255) / 256, 256, 0, stream>>>(
        v, srcloc, recloc, V2, PROF, SRCB4, RECB4, SRCB16, RECB16);

    // ---- preferred: one persistent cooperative kernel, halo-only exchange ----
    void* args[] = {
        (void*)&WF0, (void*)&WF1, (void*)&PY0, (void*)&PY1, (void*)&PX0, (void*)&PX1,
        (void*)&V2, (void*)&PROF, (void*)&SRCB16, (void*)&RECB16, (void*)&PROG,
        (void*)&srcloc, (void*)&recloc, (void*)&amps, (void*)&out
    };
    hipError_t e = hipLaunchCooperativeKernel((void*)persist_kernel,
                                              dim3(NWG2), dim3(512), args, 0, stream);

    // ---- fallback: verified r5 250-launch loop ----
    if (e != hipSuccess) {
        for (int t = 0; t < NTT; t++) {
            const bool o = (t & 1);
            step_kernel<<<NWG, 256, 0, stream>>>(
                o ? WF1 : WF0, o ? WF0 : WF1,
                o ? PY1 : PY0, o ? PY0 : PY1,
                o ? PX1 : PX0, o ? PX0 : PX1,
                ZY, ZX, V2, PROF, SRCB4, RECB4,
                srcloc, recloc, amps, out, t);
        }
    }
}

// Round 11
// 1369.091 us; speedup vs baseline: 1.1196x; 1.0947x over previous
//
#include <hip/hip_runtime.h>
#include <cstdint>

// ---------------- problem constants ----------------
#define NYD   256
#define NXD   256
#define PADC  22            // PML + FD_PAD
#define NYP_  300           // NY + 2*PAD
#define NXP_  300
#define NTT   250
#define NSHOT_ 2
#define NSRC_  8
#define NREC_  64
#define DT_   0.0005f

// guarded-array geometry
#define GDN   28
#define STP   356           // NXP_ + 2*GDN (multiple of 4 -> float4 alignment holds)
#define FP    (STP*STP)     // per-shot field words

// tile geometry: 64x8 output tile, 512 threads, 1 cell/thread
#define NTX   5             // x-tiles
#define NTY   38            // ceil(300/8): top tile has 4 overhang rows (guard-absorbed)
#define TPS   190           // tiles per shot
#define NWG   380           // total blocks = 8*47+4 -> bijective XCD swizzle

// ---------------- zero workspace ----------------
__global__ void zero_kernel(float* __restrict__ p, long n) {
    long i = (long)blockIdx.x * blockDim.x + threadIdx.x;
    long stride = (long)gridDim.x * blockDim.x;
    for (; i < n; i += stride) p[i] = 0.0f;
}

// ---------------- setup: v2dt2, PML profiles, src/rec tile bins ----------------
__global__ void populate_kernel(const float* __restrict__ v,
                                const int* __restrict__ srcloc,
                                const int* __restrict__ recloc,
                                float* __restrict__ v2dt2,   // [FP], guard stays 0
                                float* __restrict__ prof,    // [2*STP]: a, b (guard 0)
                                unsigned* __restrict__ srcbin,            // [2][TPS]
                                unsigned long long* __restrict__ recbin) { // [2][TPS]
    int i = blockIdx.x * 256 + threadIdx.x;

    if (i < NYP_ * NXP_) {
        int y = i / NXP_, x = i % NXP_;
        int vy = min(max(y - PADC, 0), NYD - 1);
        int vx = min(max(x - PADC, 0), NXD - 1);
        float vv = v[vy * NXD + vx];
        v2dt2[(y + GDN) * STP + (x + GDN)] = vv * vv * (DT_ * DT_);
    }

    if (i < NYP_) {  // DY == DX and NYP == NXP: one profile pair serves both axes
        float fi = (float)i;
        float d = fmaxf(22.0f - fi, fi - 277.0f);
        float frac = fminf(fmaxf(d * (1.0f / 20.0f), 0.0f), 1.0f);
        float sigma_max = 3.0f * 4000.0f * logf(1000.0f) / (2.0f * 20.0f * 5.0f);
        float sigma = sigma_max * frac * frac;
        float alpha = 3.14159265358979323846f * 25.0f * (1.0f - frac);
        float b = expf(-(sigma + alpha) * DT_);
        float a = sigma / (sigma + alpha + 1e-9f) * (b - 1.0f);
        prof[GDN + i] = a;
        prof[STP + GDN + i] = b;
    }

    if (i < NSHOT_ * NSRC_) {
        int sy = srcloc[2 * i] + PADC;       // [22,278)
        int sx = srcloc[2 * i + 1] + PADC;
        int shot = i / NSRC_;
        atomicOr(&srcbin[shot * TPS + (sy / 8) * NTX + (sx / 64)], 1u << (i % NSRC_));
    }

    if (i >= 1024 && i < 1024 + NSHOT_ * NREC_) {
        int j = i - 1024;
        int ry = recloc[2 * j] + PADC;
        int rx = recloc[2 * j + 1] + PADC;
        int shot = j / NREC_;
        atomicOr(&recbin[shot * TPS + (ry / 8) * NTX + (rx / 64)], 1ull << (j % NREC_));
    }
}

// ---------------- one time step, LDS-staged (r5 math verbatim, 64x8 tiles) ----------------
// 64x8 tile per 512-thread block, 1 cell/thread. Stage wf/psi tiles via float4
// into LDS (independent loads -> one latency exposure), stencil reads from LDS
// (64-consecutive per wave -> conflict-free). zeta/wfm/v2 self-cell coalesced.
// vs r5 (64x4, 750 WGs): half the workgroups to ramp/drain; staging
// amplification 3.375 -> 2.25 staged-cells/cell. Math and guard proof
// unchanged: guard ring GDN=28 (always zero; prof/v2 zero there) keeps every
// staged access in-bounds and the Dirichlet boundary exact. Overhang cells
// (x>=300, or y>=300 in the top tile) compute and store exact zeros into the
// guard harmlessly (v2=0, prof=0 -> wf/psi stay 0 forever).
// Bijective XCD swizzle (380 = 8*47+4, m204 formula) gives each XCD a
// contiguous tile band for L2 locality of halo re-reads.
__global__ __launch_bounds__(512) void step_kernel(
    const float* __restrict__ wfc_g,   // wf(t)   [2][FP]
    float* __restrict__ wfn_g,         // wf(t-1) in / wf(t+1) out
    const float* __restrict__ pyr_g, float* __restrict__ pyw_g,
    const float* __restrict__ pxr_g, float* __restrict__ pxw_g,
    float* __restrict__ zy_g, float* __restrict__ zx_g,
    const float* __restrict__ v2_g, const float* __restrict__ prof,
    const unsigned* __restrict__ srcbin,
    const unsigned long long* __restrict__ recbin,
    const int* __restrict__ srcloc, const int* __restrict__ recloc,
    const float* __restrict__ amps,   // [NSHOT][NSRC][NT]
    float* __restrict__ out,          // [NSHOT][NREC][NT]
    int t) {
    // bijective XCD swizzle: NWG=380, q=47, r=4
    const int orig = blockIdx.x;
    const int xcd = orig & 7, idx = orig >> 3;
    const int wgid = ((xcd < 4) ? xcd * 48 : 4 * 48 + (xcd - 4) * 47) + idx;
    const int shot = wgid / TPS;
    const int tl   = wgid - shot * TPS;
    const int ty0  = (tl / NTX) * 8;
    const int tx0  = (tl % NTX) * 64;

    const float* wfc = wfc_g + shot * FP;
    float*       wfn = wfn_g + shot * FP;
    const float* pyr = pyr_g + shot * FP;
    float*       pyw = pyw_g + shot * FP;
    const float* pxr = pxr_g + shot * FP;
    float*       pxw = pxw_g + shot * FP;
    float*       zyg = zy_g  + shot * FP;
    float*       zxg = zx_g  + shot * FP;

    __shared__ float swf[16][72];    // wf(t): rows ty0-4..ty0+11, cols tx0-4..tx0+67
    __shared__ float spy[12][64];    // psiy:  rows ty0-2..ty0+9,  cols tx0..tx0+63
    __shared__ float spx[8][72];     // psix:  rows ty0..ty0+7,    cols tx0-4..tx0+67
    __shared__ float sya[12], syb[12], sxa[68], sxb[68];
    __shared__ int   ssy[NSRC_], ssx[NSRC_], sry[NREC_], srx[NREC_];
    __shared__ unsigned sbs;
    __shared__ unsigned long long sbr;

    const int tid = threadIdx.x;
    const int lx = tid & 63, ly = tid >> 6;
    const int y = ty0 + ly, x = tx0 + lx;
    const int g = (y + GDN) * STP + (x + GDN);

    // self-cell state (independent scalar loads, coalesced)
    float wm = wfn[g];
    float zy = zyg[g];
    float zx = zxg[g];
    float vd = v2_g[g];

    // staged loads (624 float4 over 512 threads, all independent)
    if (tid < 288) {                              // swf: 16 x 18 float4
        int rr = tid / 18, cc = tid % 18;
        *reinterpret_cast<float4*>(&swf[rr][cc * 4]) =
            *(reinterpret_cast<const float4*>(wfc + (ty0 - 4 + rr + GDN) * STP + (tx0 - 4 + GDN)) + cc);
    } else if (tid < 480) {                       // spy: 12 x 16 float4
        int l = tid - 288, rr = l / 16, cc = l % 16;
        *reinterpret_cast<float4*>(&spy[rr][cc * 4]) =
            *(reinterpret_cast<const float4*>(pyr + (ty0 - 2 + rr + GDN) * STP + (tx0 + GDN)) + cc);
    } else {                                      // spx: first 32 of 8 x 18 float4
        int l = tid - 480, rr = l / 18, cc = l % 18;
        *reinterpret_cast<float4*>(&spx[rr][cc * 4]) =
            *(reinterpret_cast<const float4*>(pxr + (ty0 + rr + GDN) * STP + (tx0 - 4 + GDN)) + cc);
    }
    if (tid < 112) {                              // spx: remaining 112 float4
        int l = tid + 32, rr = l / 18, cc = l % 18;
        *reinterpret_cast<float4*>(&spx[rr][cc * 4]) =
            *(reinterpret_cast<const float4*>(pxr + (ty0 + rr + GDN) * STP + (tx0 - 4 + GDN)) + cc);
    }
    if (tid < 12) {
        sya[tid] = prof[GDN + ty0 - 2 + tid];
        syb[tid] = prof[STP + GDN + ty0 - 2 + tid];
    }
    if (tid < 68) {
        sxa[tid] = prof[GDN + tx0 - 2 + tid];
        sxb[tid] = prof[STP + GDN + tx0 - 2 + tid];
    }
    if (tid < NSRC_) {
        ssy[tid] = srcloc[(shot * NSRC_ + tid) * 2]     + PADC;
        ssx[tid] = srcloc[(shot * NSRC_ + tid) * 2 + 1] + PADC;
    }
    if (tid < NREC_) {
        sry[tid] = recloc[(shot * NREC_ + tid) * 2]     + PADC;
        srx[tid] = recloc[(shot * NREC_ + tid) * 2 + 1] + PADC;
    }
    if (tid == 0) {
        sbs = srcbin[shot * TPS + tl];
        sbr = recbin[shot * TPS + tl];
    }
    __syncthreads();

    const float ih  = 0.2f;    // 1/DY
    const float ih2 = 0.04f;   // 1/DY^2
    const float C1A = 2.0f / 3.0f, C1B = 1.0f / 12.0f;
    const float C2A = 4.0f / 3.0f, C2B = -1.0f / 12.0f, C2C = -2.5f;

    float wy[9];
#pragma unroll
    for (int k = 0; k < 9; k++) wy[k] = swf[ly + k][lx + 4];
    float wx[9];
#pragma unroll
    for (int k = 0; k < 9; k++) wx[k] = (k == 4) ? wy[4] : swf[ly + 4][lx + k];

    float d2y = (C2B * (wy[2] + wy[6]) + C2A * (wy[3] + wy[5]) + C2C * wy[4]) * ih2;
    float d2x = (C2B * (wx[2] + wx[6]) + C2A * (wx[3] + wx[5]) + C2C * wx[4]) * ih2;

    float pny[5], pnx[5];
#pragma unroll
    for (int j = 0; j < 5; j++) {
        float dwdy = (C1A * (wy[j + 3] - wy[j + 1]) - C1B * (wy[j + 4] - wy[j])) * ih;
        pny[j] = syb[ly + j] * spy[ly + j][lx] + sya[ly + j] * dwdy;
        float dwdx = (C1A * (wx[j + 3] - wx[j + 1]) - C1B * (wx[j + 4] - wx[j])) * ih;
        pnx[j] = sxb[lx + j] * spx[ly][lx + j + 2] + sxa[lx + j] * dwdx;
    }

    float dpsiy = (C1A * (pny[3] - pny[1]) - C1B * (pny[4] - pny[0])) * ih;
    float dpsix = (C1A * (pnx[3] - pnx[1]) - C1B * (pnx[4] - pnx[0])) * ih;

    float ay_ = sya[ly + 2], by_ = syb[ly + 2];
    float ax_ = sxa[lx + 2], bx_ = sxb[lx + 2];

    zy = by_ * zy + ay_ * (d2y + dpsiy);
    zx = bx_ * zx + ax_ * (d2x + dpsix);

    float lap = d2y + d2x + dpsiy + dpsix + zy + zx;
    float wfp = 2.0f * wy[4] - wm + vd * lap;

    // source injection (matches reference order: before store & record)
    if (sbs) {
#pragma unroll
        for (int q = 0; q < NSRC_; q++)
            if ((sbs & (1u << q)) && ssy[q] == y && ssx[q] == x)
                wfp += vd * amps[(shot * NSRC_ + q) * NTT + t];
    }

    wfn[g] = wfp;
    pyw[g] = pny[2];
    pxw[g] = pnx[2];
    zyg[g] = zy;
    zxg[g] = zx;

    unsigned long long rb = sbr;
    while (rb) {
        int r = __ffsll(rb) - 1;
        rb &= rb - 1;
        if (sry[r] == y && srx[r] == x)
            out[(shot * NREC_ + r) * NTT + t] = wfp;
    }
}

// ---------------- host ----------------
extern "C" void kernel_launch(void* const* d_in, const int* in_sizes, int n_in,
                              void* d_out, int out_size, void* d_ws, size_t ws_size,
                              hipStream_t stream) {
    const float* v      = (const float*)d_in[0];
    const float* amps   = (const float*)d_in[1];
    const int*   srcloc = (const int*)d_in[2];
    const int*   recloc = (const int*)d_in[3];
    float* out = (float*)d_out;

    float* base = (float*)d_ws;
    float* WF0 = base;             // each: [2 shots][FP]
    float* WF1 = WF0 + 2L * FP;
    float* PY0 = WF1 + 2L * FP;
    float* PY1 = PY0 + 2L * FP;
    float* PX0 = PY1 + 2L * FP;
    float* PX1 = PX0 + 2L * FP;
    float* ZY  = PX1 + 2L * FP;    // in-place (self-cell)
    float* ZX  = ZY  + 2L * FP;
    float* V2  = ZX  + 2L * FP;    // [FP], shot-independent
    float* PROF = V2 + FP;         // [2*STP] (even word count -> 8B alignment below)
    unsigned long long* RECBIN = (unsigned long long*)(PROF + 2 * STP);   // [2][TPS] = 380 ull
    unsigned* SRCBIN = (unsigned*)(RECBIN + NSHOT_ * TPS);                // [2][TPS] = 380 u32

    const long total_words = 17L * FP + 2 * STP + 2L * NSHOT_ * TPS + NSHOT_ * TPS;

    zero_kernel<<<2048, 256, 0, stream>>>(base, total_words);
    populate_kernel<<<(NYP_ * NXP_ + 255) / 256, 256, 0, stream>>>(
        v, srcloc, recloc, V2, PROF, SRCBIN, RECBIN);

    for (int t = 0; t < NTT; t++) {
        const bool o = (t & 1);
        step_kernel<<<NWG, 512, 0, stream>>>(
            o ? WF1 : WF0, o ? WF0 : WF1,
            o ? PY1 : PY0, o ? PY0 : PY1,
            o ? PX1 : PX0, o ? PX0 : PX1,
            ZY, ZX, V2, PROF, SRCBIN, RECBIN,
            srcloc, recloc, amps, out, t);
    }
}